// Round 7
// baseline (162.390 us; speedup 1.0000x reference)
//
#include <hip/hip_runtime.h>

// EdgeLoss: mean |sobel_edge(pred) - sobel_edge(target)| over [16,3,512,512] fp32.
// Depthwise 3x3 Sobel (zero pad), edge = sqrt(gx^2+gy^2+1e-6).
// One wave = full 512-wide x 8-tall band (each lane: 8 cols x 8 rows).
// X-halo via __shfl lane+-1 (lane 0/63 -> zero pad): no scalar halo loads.
// 4-slot circular row buffer, distance-1 prefetch, hardware sqrt.

#define EW 512
#define EH 512
#define EPLANE (EH * EW)               // 262144
#define NPLANES 48                     // 2*8 images * 3 channels
#define TOTAL_PX (NPLANES * EPLANE)    // 12582912
#define ROWS_PT 8
#define BANDS (EH / ROWS_PT)           // 64 bands/plane
#define NWAVES (NPLANES * BANDS)       // 3072
#define BLOCKS_MAIN (NWAVES / 4)       // 768 (4 waves/block)

__device__ __forceinline__ void load_row8(float* a, const float* __restrict__ p,
                                          bool valid) {
    if (valid) {
        float4 c0 = *reinterpret_cast<const float4*>(p);
        float4 c1 = *reinterpret_cast<const float4*>(p + 4);
        a[0] = c0.x; a[1] = c0.y; a[2] = c0.z; a[3] = c0.w;
        a[4] = c1.x; a[5] = c1.y; a[6] = c1.z; a[7] = c1.w;
    } else {
        a[0] = a[1] = a[2] = a[3] = a[4] = a[5] = a[6] = a[7] = 0.f;
    }
}

// extended access: j in [-1,8]; -1 -> l, 8 -> r (compile-time j)
#define EXT(arr, l, r, j) ((j) < 0 ? (l) : ((j) > 7 ? (r) : (arr)[(j) < 0 ? 0 : ((j) > 7 ? 7 : (j))]))

__global__ __launch_bounds__(256, 4) void edge_main(const float* __restrict__ pred,
                                                    const float* __restrict__ tgt,
                                                    float* __restrict__ partial) {
    const int lane = threadIdx.x & 63;
    const int w = blockIdx.x * 4 + (threadIdx.x >> 6);  // global wave id 0..3071
    const int plane = w >> 6;
    const int band = w & 63;
    const int y0 = band << 3;
    const int x0 = lane << 3;

    const float* __restrict__ pbase = pred + plane * EPLANE + y0 * EW + x0;
    const float* __restrict__ qbase = tgt  + plane * EPLANE + y0 * EW + x0;

    // circular buffer: row offset k in [-1,8] lives in slot (k+1)&3
    float P[4][8], T[4][8];
    load_row8(P[0], pbase - EW, band > 0);      // k=-1
    load_row8(T[0], qbase - EW, band > 0);
    load_row8(P[1], pbase,      true);          // k=0
    load_row8(T[1], qbase,      true);
    load_row8(P[2], pbase + EW, true);          // k=1 (y0+1 <= 505)
    load_row8(T[2], qbase + EW, true);

    float sum = 0.f;
#pragma unroll
    for (int r = 0; r < ROWS_PT; ++r) {
        // prefetch row k=r+2 into slot (r+3)&3 (consumed next iteration)
        if (r < ROWS_PT - 1) {
            const bool v = (y0 + r + 2) < EH;   // wave-uniform
            load_row8(P[(r + 3) & 3], pbase + (r + 2) * EW, v);
            load_row8(T[(r + 3) & 3], qbase + (r + 2) * EW, v);
        }
        float (&Pt)[8] = P[r & 3];
        float (&Pm)[8] = P[(r + 1) & 3];
        float (&Pb)[8] = P[(r + 2) & 3];
        float (&Tt)[8] = T[r & 3];
        float (&Tm)[8] = T[(r + 1) & 3];
        float (&Tb)[8] = T[(r + 2) & 3];

        // x-halo via shuffles (data loaded >=1 iteration ago: no fresh vm wait)
        float ptl = __shfl_up(Pt[7], 1);  ptl = lane ? ptl : 0.f;
        float pml = __shfl_up(Pm[7], 1);  pml = lane ? pml : 0.f;
        float pbl = __shfl_up(Pb[7], 1);  pbl = lane ? pbl : 0.f;
        float ttl = __shfl_up(Tt[7], 1);  ttl = lane ? ttl : 0.f;
        float tml = __shfl_up(Tm[7], 1);  tml = lane ? tml : 0.f;
        float tbl = __shfl_up(Tb[7], 1);  tbl = lane ? tbl : 0.f;
        float ptr_ = __shfl_down(Pt[0], 1);  ptr_ = (lane < 63) ? ptr_ : 0.f;
        float pmr = __shfl_down(Pm[0], 1);   pmr  = (lane < 63) ? pmr  : 0.f;
        float pbr = __shfl_down(Pb[0], 1);   pbr  = (lane < 63) ? pbr  : 0.f;
        float ttr = __shfl_down(Tt[0], 1);   ttr  = (lane < 63) ? ttr  : 0.f;
        float tmr = __shfl_down(Tm[0], 1);   tmr  = (lane < 63) ? tmr  : 0.f;
        float tbr = __shfl_down(Tb[0], 1);   tbr  = (lane < 63) ? tbr  : 0.f;

#pragma unroll
        for (int i = 0; i < 8; ++i) {
            float pt_m = EXT(Pt, ptl, ptr_, i - 1), pt_p = EXT(Pt, ptl, ptr_, i + 1);
            float pm_m = EXT(Pm, pml, pmr, i - 1),  pm_p = EXT(Pm, pml, pmr, i + 1);
            float pb_m = EXT(Pb, pbl, pbr, i - 1),  pb_p = EXT(Pb, pbl, pbr, i + 1);
            float gxp = (pt_p - pt_m) + 2.f * (pm_p - pm_m) + (pb_p - pb_m);
            float gyp = (pb_m - pt_m) + 2.f * (Pb[i] - Pt[i]) + (pb_p - pt_p);
            float ep  = __builtin_amdgcn_sqrtf(gxp * gxp + gyp * gyp + 1e-6f);

            float tt_m = EXT(Tt, ttl, ttr, i - 1), tt_p = EXT(Tt, ttl, ttr, i + 1);
            float tm_m = EXT(Tm, tml, tmr, i - 1), tm_p = EXT(Tm, tml, tmr, i + 1);
            float tb_m = EXT(Tb, tbl, tbr, i - 1), tb_p = EXT(Tb, tbl, tbr, i + 1);
            float gxt = (tt_p - tt_m) + 2.f * (tm_p - tm_m) + (tb_p - tb_m);
            float gyt = (tb_m - tt_m) + 2.f * (Tb[i] - Tt[i]) + (tb_p - tt_p);
            float et  = __builtin_amdgcn_sqrtf(gxt * gxt + gyt * gyt + 1e-6f);

            sum += fabsf(ep - et);
        }
    }

    // wave-64 shuffle reduce
    for (int off = 32; off > 0; off >>= 1)
        sum += __shfl_down(sum, off, 64);

    __shared__ float wsum[4];
    const int wid = threadIdx.x >> 6;
    if (lane == 0) wsum[wid] = sum;
    __syncthreads();
    if (threadIdx.x == 0)
        partial[blockIdx.x] = wsum[0] + wsum[1] + wsum[2] + wsum[3];
}

__global__ __launch_bounds__(256) void edge_final(const float* __restrict__ partial,
                                                  int n, float* __restrict__ out) {
    double s = 0.0;
    for (int i = threadIdx.x; i < n; i += 256) s += (double)partial[i];
    __shared__ double sd[256];
    sd[threadIdx.x] = s;
    __syncthreads();
    for (int k = 128; k > 0; k >>= 1) {
        if (threadIdx.x < k) sd[threadIdx.x] += sd[threadIdx.x + k];
        __syncthreads();
    }
    if (threadIdx.x == 0) out[0] = (float)(sd[0] / (double)TOTAL_PX);
}

extern "C" void kernel_launch(void* const* d_in, const int* in_sizes, int n_in,
                              void* d_out, int out_size, void* d_ws, size_t ws_size,
                              hipStream_t stream) {
    const float* pred = (const float*)d_in[0];
    const float* tgt  = (const float*)d_in[1];
    float* partial = (float*)d_ws;   // BLOCKS_MAIN floats of scratch
    float* out = (float*)d_out;

    edge_main<<<BLOCKS_MAIN, 256, 0, stream>>>(pred, tgt, partial);
    edge_final<<<1, 256, 0, stream>>>(partial, BLOCKS_MAIN, out);
}

// Round 9
// 119.496 us; speedup vs baseline: 1.3590x; 1.3590x over previous
//
#include <hip/hip_runtime.h>

// EdgeLoss: mean |sobel_edge(pred) - sobel_edge(target)| over [16,3,512,512] fp32.
// Separable Sobel: s = t+2m+b, d = b-t; gx = s[x+1]-s[x-1], gy = d[x-1]+2d[x]+d[x+1].
// One wave spans the full 512-px row (lane = 8 cols); x-halo on s/d via __shfl.
// 3-slot rolling row window, 4 rows per thread, no VGPR cap (avoid spills).

#define EW 512
#define EH 512
#define EPLANE (EH * EW)               // 262144
#define NPLANES 48                     // 2*8 images * 3 channels
#define TOTAL_PX (NPLANES * EPLANE)    // 12582912
#define ROWS_PT 4
#define BANDS (EH / ROWS_PT)           // 128 bands/plane
#define NWAVES (NPLANES * BANDS)       // 6144
#define BLOCKS_MAIN (NWAVES / 4)       // 1536 (4 waves/block, 24 waves/CU)

__device__ __forceinline__ void load_row8(float* a, const float* __restrict__ p,
                                          bool valid) {
    if (valid) {
        float4 c0 = *reinterpret_cast<const float4*>(p);
        float4 c1 = *reinterpret_cast<const float4*>(p + 4);
        a[0] = c0.x; a[1] = c0.y; a[2] = c0.z; a[3] = c0.w;
        a[4] = c1.x; a[5] = c1.y; a[6] = c1.z; a[7] = c1.w;
    } else {
        a[0] = a[1] = a[2] = a[3] = a[4] = a[5] = a[6] = a[7] = 0.f;
    }
}

// Sobel edge for 8 px of one row from a 3-row window, separable form.
__device__ __forceinline__ void sobel_edge8(const float* Rt, const float* Rm,
                                            const float* Rb, int lane, float* e) {
    float s[8], d[8];
#pragma unroll
    for (int j = 0; j < 8; ++j) {
        s[j] = __builtin_fmaf(2.f, Rm[j], Rt[j] + Rb[j]);
        d[j] = Rb[j] - Rt[j];
    }
    float sl = __shfl_up(s[7], 1);   sl = lane ? sl : 0.f;
    float dl = __shfl_up(d[7], 1);   dl = lane ? dl : 0.f;
    float sr = __shfl_down(s[0], 1); sr = (lane < 63) ? sr : 0.f;
    float dr = __shfl_down(d[0], 1); dr = (lane < 63) ? dr : 0.f;
#pragma unroll
    for (int i = 0; i < 8; ++i) {
        float sm = (i == 0) ? sl : s[i - 1];
        float sp = (i == 7) ? sr : s[i + 1];
        float dm = (i == 0) ? dl : d[i - 1];
        float dp = (i == 7) ? dr : d[i + 1];
        float gx = sp - sm;
        float gy = __builtin_fmaf(2.f, d[i], dm + dp);
        e[i] = __builtin_amdgcn_sqrtf(
                   __builtin_fmaf(gx, gx, __builtin_fmaf(gy, gy, 1e-6f)));
    }
}

__global__ __launch_bounds__(256) void edge_main(const float* __restrict__ pred,
                                                 const float* __restrict__ tgt,
                                                 float* __restrict__ partial) {
    const int lane = threadIdx.x & 63;
    const int w = blockIdx.x * 4 + (threadIdx.x >> 6);  // wave id 0..6143
    const int plane = w >> 7;                           // 128 bands/plane
    const int band = w & 127;
    const int y0 = band << 2;
    const int x0 = lane << 3;

    const float* __restrict__ pbase = pred + plane * EPLANE + y0 * EW + x0;
    const float* __restrict__ qbase = tgt  + plane * EPLANE + y0 * EW + x0;

    // rolling window: row offset k in [-1, 4] lives in slot (k+1)%3
    float P[3][8], T[3][8];
    load_row8(P[0], pbase - EW, band > 0);   // k=-1
    load_row8(T[0], qbase - EW, band > 0);
    load_row8(P[1], pbase,      true);       // k=0
    load_row8(T[1], qbase,      true);

    float sum = 0.f;
#pragma unroll
    for (int r = 0; r < ROWS_PT; ++r) {
        const bool v = (y0 + r + 1) < EH;    // wave-uniform; false only last band r=3
        load_row8(P[(r + 2) % 3], pbase + (r + 1) * EW, v);
        load_row8(T[(r + 2) % 3], qbase + (r + 1) * EW, v);

        float ep[8], et[8];
        sobel_edge8(P[r % 3], P[(r + 1) % 3], P[(r + 2) % 3], lane, ep);
        sobel_edge8(T[r % 3], T[(r + 1) % 3], T[(r + 2) % 3], lane, et);
#pragma unroll
        for (int i = 0; i < 8; ++i)
            sum += fabsf(ep[i] - et[i]);
    }

    // wave-64 shuffle reduce
    for (int off = 32; off > 0; off >>= 1)
        sum += __shfl_down(sum, off, 64);

    __shared__ float wsum[4];
    const int wid = threadIdx.x >> 6;
    if (lane == 0) wsum[wid] = sum;
    __syncthreads();
    if (threadIdx.x == 0)
        partial[blockIdx.x] = wsum[0] + wsum[1] + wsum[2] + wsum[3];
}

__global__ __launch_bounds__(256) void edge_final(const float* __restrict__ partial,
                                                  int n, float* __restrict__ out) {
    double s = 0.0;
    for (int i = threadIdx.x; i < n; i += 256) s += (double)partial[i];
    __shared__ double sd[256];
    sd[threadIdx.x] = s;
    __syncthreads();
    for (int k = 128; k > 0; k >>= 1) {
        if (threadIdx.x < k) sd[threadIdx.x] += sd[threadIdx.x + k];
        __syncthreads();
    }
    if (threadIdx.x == 0) out[0] = (float)(sd[0] / (double)TOTAL_PX);
}

extern "C" void kernel_launch(void* const* d_in, const int* in_sizes, int n_in,
                              void* d_out, int out_size, void* d_ws, size_t ws_size,
                              hipStream_t stream) {
    const float* pred = (const float*)d_in[0];
    const float* tgt  = (const float*)d_in[1];
    float* partial = (float*)d_ws;   // BLOCKS_MAIN floats of scratch
    float* out = (float*)d_out;

    edge_main<<<BLOCKS_MAIN, 256, 0, stream>>>(pred, tgt, partial);
    edge_final<<<1, 256, 0, stream>>>(partial, BLOCKS_MAIN, out);
}